// Round 2
// baseline (947.358 us; speedup 1.0000x reference)
//
#include <hip/hip_runtime.h>

#define D_IN  128
#define D_HID 64
#define D_OUT 40

// ---- degree count (dst occurrences; self-loop +1 folded into k_dinv) ----
__global__ __launch_bounds__(256) void k_deg(const int* __restrict__ dst,
                                             unsigned int* __restrict__ cnt, int E) {
    int e = blockIdx.x * 256 + threadIdx.x;
    if (e < E) atomicAdd(&cnt[dst[e]], 1u);
}

// in-place: buffer holds uint counts, becomes float dinv = rsqrt(cnt+1)
__global__ __launch_bounds__(256) void k_dinv(float* __restrict__ dinv_io, int N) {
    int i = blockIdx.x * 256 + threadIdx.x;
    if (i < N) {
        unsigned int c = ((const unsigned int*)dinv_io)[i];
        dinv_io[i] = rsqrtf((float)(c + 1u));
    }
}

// ---- h1s = (x @ W1) * dinv[row] ; 4 rows/block, thread=(row r, col) ----
__global__ __launch_bounds__(256) void k_gemm1(const float* __restrict__ x,
                                               const float* __restrict__ W1,
                                               const float* __restrict__ dinv,
                                               float* __restrict__ h1s, int N) {
    __shared__ float w[D_IN * D_HID];   // 32 KB
    __shared__ float xs[4 * D_IN];      // 2 KB
    const int tid = threadIdx.x;
    for (int i = tid; i < D_IN * D_HID; i += 256) w[i] = W1[i];
    const int row0 = blockIdx.x * 4;
    for (int i = tid; i < 4 * D_IN; i += 256) {
        int r = row0 + (i >> 7);
        xs[i] = (r < N) ? x[(size_t)row0 * D_IN + i] : 0.0f;
    }
    __syncthreads();
    const int col = tid & 63;
    const int r   = tid >> 6;
    const int row = row0 + r;
    float sum = 0.0f;
#pragma unroll
    for (int k = 0; k < D_IN; ++k)
        sum = fmaf(xs[r * D_IN + k], w[k * D_HID + col], sum);
    if (row < N) h1s[(size_t)row * D_HID + col] = sum * dinv[row];
}

// ---- h2s = (hidden @ W2) * dinv[row] ; 8 rows/block, 320 threads ----
__global__ __launch_bounds__(320) void k_gemm2(const float* __restrict__ hid,
                                               const float* __restrict__ W2,
                                               const float* __restrict__ dinv,
                                               float* __restrict__ h2s, int N) {
    __shared__ float w[D_HID * D_OUT];  // 10.25 KB
    __shared__ float xs[8 * D_HID];     // 2 KB
    const int tid = threadIdx.x;
    for (int i = tid; i < D_HID * D_OUT; i += 320) w[i] = W2[i];
    const int row0 = blockIdx.x * 8;
    for (int i = tid; i < 8 * D_HID; i += 320) {
        int r = row0 + (i >> 6);
        xs[i] = (r < N) ? hid[(size_t)row0 * D_HID + i] : 0.0f;
    }
    __syncthreads();
    const int col = tid % D_OUT;
    const int r   = tid / D_OUT;
    const int row = row0 + r;
    float sum = 0.0f;
#pragma unroll
    for (int k = 0; k < D_HID; ++k)
        sum = fmaf(xs[r * D_HID + k], w[k * D_OUT + col], sum);
    if (row < N) h2s[(size_t)row * D_OUT + col] = sum * dinv[row];
}

// ---- edge scatter: acc[dst] += h_scaled[src] (no norm needed, see factoring) ----
__global__ __launch_bounds__(256) void k_scatter1(const int* __restrict__ src,
                                                  const int* __restrict__ dst,
                                                  const float* __restrict__ h1s,
                                                  float* __restrict__ acc, int E) {
    int idx = blockIdx.x * 256 + threadIdx.x;
    int e = idx >> 6;            // 64 lanes per edge -> 256B coalesced gather
    if (e >= E) return;
    int c = idx & 63;
    int s = src[e], d = dst[e];
    atomicAdd(&acc[(size_t)d * D_HID + c], h1s[(size_t)s * D_HID + c]);
}

__global__ __launch_bounds__(256) void k_scatter2(const int* __restrict__ src,
                                                  const int* __restrict__ dst,
                                                  const float* __restrict__ h2s,
                                                  float* __restrict__ acc, int E) {
    int idx = blockIdx.x * 256 + threadIdx.x;
    int e = idx / D_OUT;
    if (e >= E) return;
    int c = idx - e * D_OUT;
    atomicAdd(&acc[(size_t)dst[e] * D_OUT + c], h2s[(size_t)src[e] * D_OUT + c]);
}

// ---- hidden = relu(dinv*(acc + h1s_selfloop) + b1), in-place into acc ----
__global__ __launch_bounds__(256) void k_fin1(const float* __restrict__ h1s,
                                              const float* __restrict__ dinv,
                                              const float* __restrict__ b1,
                                              float* __restrict__ acc, int N) {
    int idx = blockIdx.x * 256 + threadIdx.x;
    if (idx >= N * D_HID) return;
    int i = idx >> 6;
    int c = idx & 63;
    float v = dinv[i] * (acc[idx] + h1s[idx]) + b1[c];
    acc[idx] = v > 0.0f ? v : 0.0f;
}

// ---- out = dinv*(acc + h2s_selfloop) + b2, in-place into d_out ----
__global__ __launch_bounds__(256) void k_fin2(const float* __restrict__ h2s,
                                              const float* __restrict__ dinv,
                                              const float* __restrict__ b2,
                                              float* __restrict__ out, int N) {
    int idx = blockIdx.x * 256 + threadIdx.x;
    if (idx >= N * D_OUT) return;
    int i = idx / D_OUT;
    int c = idx - i * D_OUT;
    out[idx] = dinv[i] * (out[idx] + h2s[idx]) + b2[c];
}

extern "C" void kernel_launch(void* const* d_in, const int* in_sizes, int n_in,
                              void* d_out, int out_size, void* d_ws, size_t ws_size,
                              hipStream_t stream) {
    const float* x  = (const float*)d_in[0];
    const int*  eix = (const int*)d_in[1];   // [2, E] int32 per harness contract
    const float* W1 = (const float*)d_in[2];
    const float* b1 = (const float*)d_in[3];
    const float* W2 = (const float*)d_in[4];
    const float* b2 = (const float*)d_in[5];
    float* out = (float*)d_out;

    const int N = in_sizes[0] / D_IN;
    const int E = in_sizes[1] / 2;
    const int* src = eix;
    const int* dst = eix + E;

    // workspace layout (all 256B aligned): dinv | h1s | acc1(->hidden) | h2s
    char* ws = (char*)d_ws;
    size_t off = 0;
    auto alloc = [&](size_t bytes) {
        void* p = ws + off;
        off = (off + bytes + 255) & ~(size_t)255;
        return p;
    };
    float* dinv = (float*)alloc((size_t)N * 4);
    float* h1s  = (float*)alloc((size_t)N * D_HID * 4);
    float* acc1 = (float*)alloc((size_t)N * D_HID * 4);
    float* h2s  = (float*)alloc((size_t)N * D_OUT * 4);

    hipMemsetAsync(dinv, 0, (size_t)N * 4, stream);                 // uint counts
    hipMemsetAsync(acc1, 0, (size_t)N * D_HID * 4, stream);
    hipMemsetAsync(out,  0, (size_t)N * D_OUT * 4, stream);         // d_out is acc2

    k_deg <<<(E + 255) / 256, 256, 0, stream>>>(dst, (unsigned int*)dinv, E);
    k_dinv<<<(N + 255) / 256, 256, 0, stream>>>(dinv, N);

    k_gemm1<<<(N + 3) / 4, 256, 0, stream>>>(x, W1, dinv, h1s, N);
    k_scatter1<<<(int)(((size_t)E * 64 + 255) / 256), 256, 0, stream>>>(src, dst, h1s, acc1, E);
    k_fin1<<<(int)(((size_t)N * D_HID + 255) / 256), 256, 0, stream>>>(h1s, dinv, b1, acc1, N);

    k_gemm2<<<(N + 7) / 8, 320, 0, stream>>>(acc1, W2, dinv, h2s, N);
    k_scatter2<<<(int)(((size_t)E * D_OUT + 255) / 256), 256, 0, stream>>>(src, dst, h2s, out, E);
    k_fin2<<<(int)(((size_t)N * D_OUT + 255) / 256), 256, 0, stream>>>(h2s, dinv, b2, out, N);
}

// Round 3
// 649.413 us; speedup vs baseline: 1.4588x; 1.4588x over previous
//
#include <hip/hip_runtime.h>

#define D_IN  128
#define D_HID 64
#define D_OUT 40

// ---- degree count (in-degree of dst; self-loop +1 folded into k_dinv) ----
__global__ __launch_bounds__(256) void k_deg(const int* __restrict__ dst,
                                             unsigned int* __restrict__ cnt, int E) {
    int e = blockIdx.x * 256 + threadIdx.x;
    if (e < E) atomicAdd(&cnt[dst[e]], 1u);
}

__global__ __launch_bounds__(256) void k_dinv(const unsigned int* __restrict__ deg,
                                              float* __restrict__ dinv, int N) {
    int i = blockIdx.x * 256 + threadIdx.x;
    if (i < N) dinv[i] = rsqrtf((float)(deg[i] + 1u));
}

// ---- exclusive scan of deg -> offsets (3-kernel hierarchical) ----
__global__ __launch_bounds__(256) void k_scan1(const unsigned int* __restrict__ deg,
                                               unsigned int* __restrict__ off,
                                               unsigned int* __restrict__ bsum, int N) {
    __shared__ unsigned int s[256];
    const int tid = threadIdx.x;
    const int i = blockIdx.x * 256 + tid;
    unsigned int v = (i < N) ? deg[i] : 0u;
    s[tid] = v;
    __syncthreads();
    for (int d = 1; d < 256; d <<= 1) {
        unsigned int t = (tid >= d) ? s[tid - d] : 0u;
        __syncthreads();
        s[tid] += t;
        __syncthreads();
    }
    if (i < N) off[i] = s[tid] - v;              // exclusive
    if (tid == 255) bsum[blockIdx.x] = s[tid];   // block total
}

__global__ __launch_bounds__(512) void k_scan2(unsigned int* __restrict__ bsum, int NB) {
    __shared__ unsigned int s[512];
    const int tid = threadIdx.x;
    unsigned int v = (tid < NB) ? bsum[tid] : 0u;
    s[tid] = v;
    __syncthreads();
    for (int d = 1; d < 512; d <<= 1) {
        unsigned int t = (tid >= d) ? s[tid - d] : 0u;
        __syncthreads();
        s[tid] += t;
        __syncthreads();
    }
    if (tid < NB) bsum[tid] = s[tid] - v;        // exclusive over block sums
}

__global__ __launch_bounds__(256) void k_scan3(unsigned int* __restrict__ off,
                                               const unsigned int* __restrict__ bsum,
                                               int N, int E) {
    int i = blockIdx.x * 256 + threadIdx.x;
    if (i < N) off[i] += bsum[blockIdx.x];
    if (i == 0) off[N] = (unsigned int)E;
}

// ---- counting-sort fill: csr_src[segment of dst] = src ----
__global__ __launch_bounds__(256) void k_fill(const int* __restrict__ src,
                                              const int* __restrict__ dst,
                                              unsigned int* __restrict__ cursor,
                                              int* __restrict__ csr_src, int E) {
    int e = blockIdx.x * 256 + threadIdx.x;
    if (e >= E) return;
    unsigned int pos = atomicAdd(&cursor[dst[e]], 1u);
    csr_src[pos] = src[e];
}

// ---- h1s = (x @ W1) * dinv[row] ; 4 rows/block ----
__global__ __launch_bounds__(256) void k_gemm1(const float* __restrict__ x,
                                               const float* __restrict__ W1,
                                               const float* __restrict__ dinv,
                                               float* __restrict__ h1s, int N) {
    __shared__ float w[D_IN * D_HID];   // 32 KB
    __shared__ float xs[4 * D_IN];      // 2 KB
    const int tid = threadIdx.x;
    for (int i = tid; i < D_IN * D_HID; i += 256) w[i] = W1[i];
    const int row0 = blockIdx.x * 4;
    for (int i = tid; i < 4 * D_IN; i += 256) {
        int r = row0 + (i >> 7);
        xs[i] = (r < N) ? x[(size_t)row0 * D_IN + i] : 0.0f;
    }
    __syncthreads();
    const int col = tid & 63;
    const int r   = tid >> 6;
    const int row = row0 + r;
    float sum = 0.0f;
#pragma unroll
    for (int k = 0; k < D_IN; ++k)
        sum = fmaf(xs[r * D_IN + k], w[k * D_HID + col], sum);
    if (row < N) h1s[(size_t)row * D_HID + col] = sum * dinv[row];
}

// ---- h2s = (hidden @ W2) * dinv[row] ; 8 rows/block ----
__global__ __launch_bounds__(320) void k_gemm2(const float* __restrict__ hid,
                                               const float* __restrict__ W2,
                                               const float* __restrict__ dinv,
                                               float* __restrict__ h2s, int N) {
    __shared__ float w[D_HID * D_OUT];
    __shared__ float xs[8 * D_HID];
    const int tid = threadIdx.x;
    for (int i = tid; i < D_HID * D_OUT; i += 320) w[i] = W2[i];
    const int row0 = blockIdx.x * 8;
    for (int i = tid; i < 8 * D_HID; i += 320) {
        int r = row0 + (i >> 6);
        xs[i] = (r < N) ? hid[(size_t)row0 * D_HID + i] : 0.0f;
    }
    __syncthreads();
    const int col = tid % D_OUT;
    const int r   = tid / D_OUT;
    const int row = row0 + r;
    float sum = 0.0f;
#pragma unroll
    for (int k = 0; k < D_HID; ++k)
        sum = fmaf(xs[r * D_HID + k], w[k * D_OUT + col], sum);
    if (row < N) h2s[(size_t)row * D_OUT + col] = sum * dinv[row];
}

// ---- gather1: hidden[n] = relu(dinv[n]*(Σ_in h1s[src] + h1s[n]) + b1) ----
// one wave per node; lane = col (64 cols). Edge ids batch-loaded, shfl-broadcast.
__global__ __launch_bounds__(256) void k_gather1(const unsigned int* __restrict__ off,
                                                 const int* __restrict__ csr_src,
                                                 const float* __restrict__ h1s,
                                                 const float* __restrict__ dinv,
                                                 const float* __restrict__ b1,
                                                 float* __restrict__ hidden, int N) {
    const int wid  = (blockIdx.x * 256 + threadIdx.x) >> 6;
    const int lane = threadIdx.x & 63;
    if (wid >= N) return;
    const int start = (int)off[wid];
    const int end   = (int)off[wid + 1];
    float acc = h1s[(size_t)wid * D_HID + lane];   // self-loop term
    for (int base = start; base < end; base += 64) {
        const int nb = min(64, end - base);
        int sv = (base + lane < end) ? csr_src[base + lane] : 0;
        for (int j = 0; j < nb; ++j) {
            int s = __shfl(sv, j);
            acc += h1s[(size_t)s * D_HID + lane];
        }
    }
    float v = dinv[wid] * acc + b1[lane];
    hidden[(size_t)wid * D_HID + lane] = v > 0.0f ? v : 0.0f;
}

// ---- gather2: out[n] = dinv[n]*(Σ_in h2s[src] + h2s[n]) + b2 ----
__global__ __launch_bounds__(256) void k_gather2(const unsigned int* __restrict__ off,
                                                 const int* __restrict__ csr_src,
                                                 const float* __restrict__ h2s,
                                                 const float* __restrict__ dinv,
                                                 const float* __restrict__ b2,
                                                 float* __restrict__ out, int N) {
    const int wid  = (blockIdx.x * 256 + threadIdx.x) >> 6;
    const int lane = threadIdx.x & 63;
    if (wid >= N) return;
    const int start = (int)off[wid];
    const int end   = (int)off[wid + 1];
    float acc = (lane < D_OUT) ? h2s[(size_t)wid * D_OUT + lane] : 0.0f;
    for (int base = start; base < end; base += 64) {
        const int nb = min(64, end - base);
        int sv = (base + lane < end) ? csr_src[base + lane] : 0;
        for (int j = 0; j < nb; ++j) {
            int s = __shfl(sv, j);
            if (lane < D_OUT) acc += h2s[(size_t)s * D_OUT + lane];
        }
    }
    if (lane < D_OUT)
        out[(size_t)wid * D_OUT + lane] = dinv[wid] * acc + b2[lane];
}

extern "C" void kernel_launch(void* const* d_in, const int* in_sizes, int n_in,
                              void* d_out, int out_size, void* d_ws, size_t ws_size,
                              hipStream_t stream) {
    const float* x  = (const float*)d_in[0];
    const int*  eix = (const int*)d_in[1];   // [2, E] int32 per harness contract
    const float* W1 = (const float*)d_in[2];
    const float* b1 = (const float*)d_in[3];
    const float* W2 = (const float*)d_in[4];
    const float* b2 = (const float*)d_in[5];
    float* out = (float*)d_out;

    const int N = in_sizes[0] / D_IN;
    const int E = in_sizes[1] / 2;
    const int* src = eix;
    const int* dst = eix + E;
    const int NB = (N + 255) / 256;   // scan blocks (<=512 required by k_scan2)

    // workspace layout: deg | dinv | offsets(N+1) | cursor | bsums(512) | csr_src(E) | h1s | hidden
    // h2s aliases h1s (h1s dead after gather1).
    char* ws = (char*)d_ws;
    size_t off_b = 0;
    auto alloc = [&](size_t bytes) {
        void* p = ws + off_b;
        off_b = (off_b + bytes + 255) & ~(size_t)255;
        return p;
    };
    unsigned int* deg     = (unsigned int*)alloc((size_t)N * 4);
    float*        dinv    = (float*)alloc((size_t)N * 4);
    unsigned int* offsets = (unsigned int*)alloc((size_t)(N + 1) * 4);
    unsigned int* cursor  = (unsigned int*)alloc((size_t)N * 4);
    unsigned int* bsums   = (unsigned int*)alloc(512 * 4);
    int*          csr_src = (int*)alloc((size_t)E * 4);
    float*        h1s     = (float*)alloc((size_t)N * D_HID * 4);
    float*        hidden  = (float*)alloc((size_t)N * D_HID * 4);
    float*        h2s     = h1s;   // alias: h1s dead after k_gather1

    hipMemsetAsync(deg, 0, (size_t)N * 4, stream);

    // CSR build
    k_deg  <<<(E + 255) / 256, 256, 0, stream>>>(dst, deg, E);
    k_dinv <<<NB, 256, 0, stream>>>(deg, dinv, N);
    k_scan1<<<NB, 256, 0, stream>>>(deg, offsets, bsums, N);
    k_scan2<<<1, 512, 0, stream>>>(bsums, NB);
    k_scan3<<<NB, 256, 0, stream>>>(offsets, bsums, N, E);
    hipMemcpyAsync(cursor, offsets, (size_t)N * 4, hipMemcpyDeviceToDevice, stream);
    k_fill <<<(E + 255) / 256, 256, 0, stream>>>(src, dst, cursor, csr_src, E);

    // layer 1
    k_gemm1  <<<(N + 3) / 4, 256, 0, stream>>>(x, W1, dinv, h1s, N);
    k_gather1<<<(N + 3) / 4, 256, 0, stream>>>(offsets, csr_src, h1s, dinv, b1, hidden, N);

    // layer 2
    k_gemm2  <<<(N + 7) / 8, 320, 0, stream>>>(hidden, W2, dinv, h2s, N);
    k_gather2<<<(N + 3) / 4, 256, 0, stream>>>(offsets, csr_src, h2s, dinv, b2, out, N);
}